// Round 10
// baseline (1052.669 us; speedup 1.0000x reference)
//
#include <hip/hip_runtime.h>
#include <hip/hip_cooperative_groups.h>
#include <math.h>

namespace cg = cooperative_groups;

#define T_LEN  176400
#define NHARM  64
#define NBANDS 65
#define NROWS  16
#define NBLK   690    // ceil(T_LEN/256)

// 2*pi*440 in f64 (bit-identical to Python's 2.0*np.pi*440.0).
static constexpr double PHCd = 2.0 * 3.14159265358979323846 * 440.0;
// f32 linspace step as jax computes it: fl32((4.0-0.0)/176399), held in f64.
// i*DELTA32 is EXACT in f64 (18+24 < 53 mantissa bits).
static constexpr double DELTA32 = (double)(float)(4.0 / 176399.0);
// Cody-Waite two-part 2*pi (m*HI exact for the m range here).
static constexpr double TWOPI_HI = 0x1.921FB5p+2;
static constexpr double TWOPI_LO = 6.283185307179586476925287 - TWOPI_HI;
static constexpr double INV2PI   = 1.0 / 6.283185307179586476925287;

// Fused t-major cooperative kernel: compute sig for 16 rows in registers,
// grid-wide max via wsMax[block][row] + grid.sync(), normalize, single store.
__global__ __launch_bounds__(256) void ddsp_fused(
    const float* __restrict__ harm,    // [16][64]
    const float* __restrict__ nbands,  // [16][65]
    const float* __restrict__ adsr,    // [16][4]
    const float* __restrict__ gain,    // [16]
    const float* __restrict__ noise,   // [16][T]
    float* __restrict__ out,           // [16][T] final output (d_out)
    float* __restrict__ wsMax)         // [NBLK][16] block maxima (d_ws)
{
    __shared__ float4 wv[NHARM][4];    // wv[k][j] = w rows 4j..4j+3, harmonic k
    __shared__ float2 ckek[NHARM];     // {c_k, e_k}
    __shared__ float4 envA[NROWS];     // {a_f, ad_f, ads_f, adsr_f}
    __shared__ float4 envB[NROWS];     // {inv_a, inv_d, inv_r, sus}
    __shared__ float2 nlg[NROWS];      // {nl, g}
    __shared__ float  redbuf[4][NROWS];
    __shared__ float  pmbuf[16][NROWS];
    __shared__ float  invsm[NROWS];

    const int tid = threadIdx.x;

    // ---- ck/ek table (device f64, bit-identical across rounds) ----
    if (tid < NHARM) {
        const double ckd = PHCd * (double)(tid + 1);
        const float ck = (float)ckd;
        const float ek = (float)((double)ck - ckd);
        ckek[tid] = make_float2(ck, ek);
    }
    // ---- transposed weights: linear idx = k*16 + r  <-  harm[r*64 + k] ----
    {
        float* wflat = (float*)wv;
        #pragma unroll
        for (int j = 0; j < 4; ++j) {
            const int idx = tid + 256*j;
            const int k = idx >> 4, r = idx & 15;
            wflat[idx] = harm[r*NHARM + k];
        }
    }
    // ---- per-row params (exact R8/R9 f32 sequence) ----
    if (tid < NROWS) {
        const int row = tid;
        float nl = 0.0f;
        for (int j = 0; j < NBANDS; ++j) nl += nbands[row*NBANDS + j];
        nl = (nl / (float)NBANDS) * 0.1f;
        const float att = adsr[row*4+0], dcy = adsr[row*4+1],
                    sus = adsr[row*4+2], rls = adsr[row*4+3];
        int a = (int)floorf(att*0.5f*44100.0f) + 1;
        int d = (int)floorf(dcy*0.5f*44100.0f) + 1;
        int r = (int)floorf(rls*0.5f*44100.0f) + 1;
        const int tot = a + d + r;
        if (tot > T_LEN) {   // dead for U[0,1] adsr, kept for parity
            const float sc = (float)T_LEN / (float)tot;
            a = (int)floorf((float)a*sc);
            d = (int)floorf((float)d*sc);
            r = (int)floorf((float)r*sc);
        }
        int slen = T_LEN - (a+d+r); if (slen < 0) slen = 0;
        const float a_f=(float)a, d_f=(float)d, r_f=(float)r, s_f=(float)slen;
        const float ad_f = a_f + d_f;
        const float ads_f = ad_f + s_f;
        const float adsr_f = ads_f + r_f;
        envA[row] = make_float4(a_f, ad_f, ads_f, adsr_f);
        envB[row] = make_float4(1.0f/fmaxf(a_f-1.0f,1.0f),
                                1.0f/fmaxf(d_f-1.0f,1.0f),
                                1.0f/fmaxf(r_f-1.0f,1.0f), sus);
        nlg[row]  = make_float2(nl, gain[row]);
    }
    __syncthreads();

    const int t = blockIdx.x*256 + tid;
    const bool act = (t < T_LEN);

    // ---- seed: sin/cos(alpha), alpha = PHCd * (f64 of f32 t)  [== R8/R9] ----
    const double td = (double)t * DELTA32;   // exact in f64
    const float  tf = (float)td;             // jax's f32 t, bit-exact
    const double alpha = PHCd * (double)tf;
    const double mq  = rint(alpha * INV2PI);
    const double rph = (alpha - mq*TWOPI_HI) - mq*TWOPI_LO;
    const float  th  = (float)rph;
    const float  tlo = (float)(rph - (double)th);
    float sn, cs;
    sincosf(th, &sn, &cs);
    const float s1 = __builtin_fmaf(cs,  tlo, sn);
    const float c1 = __builtin_fmaf(-sn, tlo, cs);
    float S = s1, Cc = c1;

    float acc[NROWS];
    #pragma unroll
    for (int r = 0; r < NROWS; ++r) acc[r] = 0.0f;

    // ---- k-loop: sin once per (k,t), 16 row-FMAs share it [== R9] ----
    #pragma unroll 8
    for (int k = 0; k < NHARM; ++k) {
        const float2 ce = ckek[k];
        const float4 w0 = wv[k][0];
        const float4 w1 = wv[k][1];
        const float4 w2 = wv[k][2];
        const float4 w3 = wv[k][3];
        const float pp = ce.x * tf;                       // ref phase bits
        const float rr = __builtin_fmaf(ce.x, tf, -pp);   // exact residual
        const float D  = __builtin_fmaf(ce.y, tf, -rr);   // pp - k*alpha
        const float d2 = D * D;
        const float cA = __builtin_fmaf(-0.5f, d2, 1.0f);
        const float cB = __builtin_fmaf(-0.16666667f, d2, 1.0f);
        const float DB = D * cB;
        const float val = __builtin_fmaf(Cc, DB, S*cA);   // sin(kA + D)
        acc[ 0] = __builtin_fmaf(w0.x, val, acc[ 0]);
        acc[ 1] = __builtin_fmaf(w0.y, val, acc[ 1]);
        acc[ 2] = __builtin_fmaf(w0.z, val, acc[ 2]);
        acc[ 3] = __builtin_fmaf(w0.w, val, acc[ 3]);
        acc[ 4] = __builtin_fmaf(w1.x, val, acc[ 4]);
        acc[ 5] = __builtin_fmaf(w1.y, val, acc[ 5]);
        acc[ 6] = __builtin_fmaf(w1.z, val, acc[ 6]);
        acc[ 7] = __builtin_fmaf(w1.w, val, acc[ 7]);
        acc[ 8] = __builtin_fmaf(w2.x, val, acc[ 8]);
        acc[ 9] = __builtin_fmaf(w2.y, val, acc[ 9]);
        acc[10] = __builtin_fmaf(w2.z, val, acc[10]);
        acc[11] = __builtin_fmaf(w2.w, val, acc[11]);
        acc[12] = __builtin_fmaf(w3.x, val, acc[12]);
        acc[13] = __builtin_fmaf(w3.y, val, acc[13]);
        acc[14] = __builtin_fmaf(w3.z, val, acc[14]);
        acc[15] = __builtin_fmaf(w3.w, val, acc[15]);
        const float t1 = Cc * s1;
        const float t2 = S  * s1;
        const float ns = __builtin_fmaf(S,  c1,  t1);
        const float nc = __builtin_fmaf(Cc, c1, -t2);
        S = ns; Cc = nc;
    }

    // ---- epilogue: finalize sig in REGISTERS (acc becomes sig) ----
    float amr[NROWS];
    const float i_f = (float)t;
    #pragma unroll
    for (int r = 0; r < NROWS; ++r) {
        float am = 0.0f;
        if (act) {
            const float  nz = noise[(size_t)r*T_LEN + t];
            const float4 eA = envA[r];
            const float4 eB = envB[r];
            const float2 ng = nlg[r];
            float env;
            if      (i_f < eA.x) env = (eA.x > 1.0f) ? i_f * eB.x : 0.0f;
            else if (i_f < eA.y) env = __builtin_fmaf((eB.w-1.0f)*(i_f-eA.x), eB.y, 1.0f);
            else if (i_f < eA.z) env = eB.w;
            else if (i_f < eA.w) env = eB.w * (1.0f - (i_f-eA.z)*eB.z);
            else                 env = 0.0f;
            const float n  = (nz*2.0f - 1.0f) * ng.x;
            acc[r] = ((acc[r] + n) * env) * ng.y;   // final sig, stays in VGPR
            am = fabsf(acc[r]);
        }
        amr[r] = am;
    }

    // ---- per-row wave max-reduce, then block max -> wsMax[block][row] ----
    #pragma unroll
    for (int off = 32; off > 0; off >>= 1) {
        #pragma unroll
        for (int r = 0; r < NROWS; ++r)
            amr[r] = fmaxf(amr[r], __shfl_xor(amr[r], off, 64));
    }
    if ((tid & 63) == 0) {
        const int wid = tid >> 6;
        #pragma unroll
        for (int r = 0; r < NROWS; ++r) redbuf[wid][r] = amr[r];
    }
    __syncthreads();
    if (tid < NROWS) {
        const float m01 = fmaxf(redbuf[0][tid], redbuf[1][tid]);
        const float m23 = fmaxf(redbuf[2][tid], redbuf[3][tid]);
        __hip_atomic_store(&wsMax[blockIdx.x*NROWS + tid], fmaxf(m01, m23),
                           __ATOMIC_RELEASE, __HIP_MEMORY_SCOPE_AGENT);
    }

    cg::this_grid().sync();

    // ---- grid max per row: scan 690 block maxima (L2-resident, 44 KB) ----
    {
        const int row = tid & 15, chunk = tid >> 4;
        float pm = 0.0f;
        for (int b = chunk; b < NBLK; b += 16)
            pm = fmaxf(pm, __hip_atomic_load(&wsMax[b*NROWS + row],
                                             __ATOMIC_ACQUIRE, __HIP_MEMORY_SCOPE_AGENT));
        pmbuf[chunk][row] = pm;
    }
    __syncthreads();
    if (tid < NROWS) {
        float m = 0.0f;
        #pragma unroll
        for (int c = 0; c < 16; ++c) m = fmaxf(m, pmbuf[c][tid]);
        invsm[tid] = 1.0f / (m + 1e-5f);   // same recip-mul as R8/R9 (passed)
    }
    __syncthreads();

    // ---- single HBM write of the normalized output ----
    if (act) {
        #pragma unroll
        for (int r = 0; r < NROWS; ++r)
            out[(size_t)r*T_LEN + t] = acc[r] * invsm[r];
    }
}

extern "C" void kernel_launch(void* const* d_in, const int* in_sizes, int n_in,
                              void* d_out, int out_size, void* d_ws, size_t ws_size,
                              hipStream_t stream) {
    // inputs: 0=base_audio(unused) 1=harmonic_dist 2=noise_bands 3=adsr 4=gain 5=noise
    const float* harm  = (const float*)d_in[1];
    const float* nbp   = (const float*)d_in[2];
    const float* adsrp = (const float*)d_in[3];
    const float* gainp = (const float*)d_in[4];
    const float* noisp = (const float*)d_in[5];
    float* out   = (float*)d_out;
    float* wsMax = (float*)d_ws;   // NBLK*16 floats; every slot written pre-sync

    void* args[] = { (void*)&harm, (void*)&nbp, (void*)&adsrp, (void*)&gainp,
                     (void*)&noisp, (void*)&out, (void*)&wsMax };
    hipLaunchCooperativeKernel((const void*)ddsp_fused,
                               dim3(NBLK), dim3(256), args, 0, stream);
}

// Round 11
// 180.119 us; speedup vs baseline: 5.8443x; 5.8443x over previous
//
#include <hip/hip_runtime.h>
#include <math.h>

#define T_LEN  176400
#define NHARM  64
#define NBANDS 65
#define NROWS  16
#define NBLK   690    // ceil(T_LEN/256); 690 <= 768 guaranteed-resident slots

// 2*pi*440 in f64 (bit-identical to Python's 2.0*np.pi*440.0).
static constexpr double PHCd = 2.0 * 3.14159265358979323846 * 440.0;
// f32 linspace step as jax computes it: fl32((4.0-0.0)/176399), held in f64.
// i*DELTA32 is EXACT in f64 (18+24 < 53 mantissa bits).
static constexpr double DELTA32 = (double)(float)(4.0 / 176399.0);
// Cody-Waite two-part 2*pi (m*HI exact for the m range here).
static constexpr double TWOPI_HI = 0x1.921FB5p+2;
static constexpr double TWOPI_LO = 6.283185307179586476925287 - TWOPI_HI;
static constexpr double INV2PI   = 1.0 / 6.283185307179586476925287;

// Fused t-major kernel with a HAND-ROLLED grid barrier (no cooperative groups,
// no external calls -> normal regalloc; R10's cg::sync forced VGPR=32 + spills).
// Co-residency: __launch_bounds__(256,3) -> 3 blocks/CU -> 768 slots >= 690.
__global__ __launch_bounds__(256, 3) void ddsp_fused(
    const float* __restrict__ harm,    // [16][64]
    const float* __restrict__ nbands,  // [16][65]
    const float* __restrict__ adsr,    // [16][4]
    const float* __restrict__ gain,    // [16]
    const float* __restrict__ noise,   // [16][T]
    float* __restrict__ out,           // [16][T] final output (d_out)
    unsigned int* __restrict__ rowmax, // [16] in ws (zeroed by memset)
    unsigned int* __restrict__ counter)// [1]  in ws (zeroed by memset)
{
    __shared__ float4 wv[NHARM][4];    // wv[k][j] = w rows 4j..4j+3, harmonic k
    __shared__ float2 ckek[NHARM];     // {c_k, e_k}
    __shared__ float4 envA[NROWS];     // {a_f, ad_f, ads_f, adsr_f}
    __shared__ float4 envB[NROWS];     // {inv_a, inv_d, inv_r, sus}
    __shared__ float2 nlg[NROWS];      // {nl, g}
    __shared__ float  redbuf[4][NROWS];
    __shared__ float  invsm[NROWS];

    const int tid = threadIdx.x;

    // ---- ck/ek table (device f64, bit-identical across rounds) ----
    if (tid < NHARM) {
        const double ckd = PHCd * (double)(tid + 1);
        const float ck = (float)ckd;
        const float ek = (float)((double)ck - ckd);
        ckek[tid] = make_float2(ck, ek);
    }
    // ---- transposed weights: linear idx = k*16 + r  <-  harm[r*64 + k] ----
    {
        float* wflat = (float*)wv;
        #pragma unroll
        for (int j = 0; j < 4; ++j) {
            const int idx = tid + 256*j;
            const int k = idx >> 4, r = idx & 15;
            wflat[idx] = harm[r*NHARM + k];
        }
    }
    // ---- per-row params (exact R8/R9 f32 sequence) ----
    if (tid < NROWS) {
        const int row = tid;
        float nl = 0.0f;
        for (int j = 0; j < NBANDS; ++j) nl += nbands[row*NBANDS + j];
        nl = (nl / (float)NBANDS) * 0.1f;
        const float att = adsr[row*4+0], dcy = adsr[row*4+1],
                    sus = adsr[row*4+2], rls = adsr[row*4+3];
        int a = (int)floorf(att*0.5f*44100.0f) + 1;
        int d = (int)floorf(dcy*0.5f*44100.0f) + 1;
        int r = (int)floorf(rls*0.5f*44100.0f) + 1;
        const int tot = a + d + r;
        if (tot > T_LEN) {   // dead for U[0,1] adsr, kept for parity
            const float sc = (float)T_LEN / (float)tot;
            a = (int)floorf((float)a*sc);
            d = (int)floorf((float)d*sc);
            r = (int)floorf((float)r*sc);
        }
        int slen = T_LEN - (a+d+r); if (slen < 0) slen = 0;
        const float a_f=(float)a, d_f=(float)d, r_f=(float)r, s_f=(float)slen;
        const float ad_f = a_f + d_f;
        const float ads_f = ad_f + s_f;
        const float adsr_f = ads_f + r_f;
        envA[row] = make_float4(a_f, ad_f, ads_f, adsr_f);
        envB[row] = make_float4(1.0f/fmaxf(a_f-1.0f,1.0f),
                                1.0f/fmaxf(d_f-1.0f,1.0f),
                                1.0f/fmaxf(r_f-1.0f,1.0f), sus);
        nlg[row]  = make_float2(nl, gain[row]);
    }
    __syncthreads();

    const int t = blockIdx.x*256 + tid;
    const bool act = (t < T_LEN);

    // ---- seed: sin/cos(alpha), alpha = PHCd * (f64 of f32 t)  [== R8/R9] ----
    const double td = (double)t * DELTA32;   // exact in f64
    const float  tf = (float)td;             // jax's f32 t, bit-exact
    const double alpha = PHCd * (double)tf;
    const double mq  = rint(alpha * INV2PI);
    const double rph = (alpha - mq*TWOPI_HI) - mq*TWOPI_LO;
    const float  th  = (float)rph;
    const float  tlo = (float)(rph - (double)th);
    float sn, cs;
    sincosf(th, &sn, &cs);
    const float s1 = __builtin_fmaf(cs,  tlo, sn);
    const float c1 = __builtin_fmaf(-sn, tlo, cs);
    float S = s1, Cc = c1;

    float acc[NROWS];
    #pragma unroll
    for (int r = 0; r < NROWS; ++r) acc[r] = 0.0f;

    // ---- k-loop: sin once per (k,t), 16 row-FMAs share it [== R9] ----
    #pragma unroll 8
    for (int k = 0; k < NHARM; ++k) {
        const float2 ce = ckek[k];
        const float4 w0 = wv[k][0];
        const float4 w1 = wv[k][1];
        const float4 w2 = wv[k][2];
        const float4 w3 = wv[k][3];
        const float pp = ce.x * tf;                       // ref phase bits
        const float rr = __builtin_fmaf(ce.x, tf, -pp);   // exact residual
        const float D  = __builtin_fmaf(ce.y, tf, -rr);   // pp - k*alpha
        const float d2 = D * D;
        const float cA = __builtin_fmaf(-0.5f, d2, 1.0f);
        const float cB = __builtin_fmaf(-0.16666667f, d2, 1.0f);
        const float DB = D * cB;
        const float val = __builtin_fmaf(Cc, DB, S*cA);   // sin(kA + D)
        acc[ 0] = __builtin_fmaf(w0.x, val, acc[ 0]);
        acc[ 1] = __builtin_fmaf(w0.y, val, acc[ 1]);
        acc[ 2] = __builtin_fmaf(w0.z, val, acc[ 2]);
        acc[ 3] = __builtin_fmaf(w0.w, val, acc[ 3]);
        acc[ 4] = __builtin_fmaf(w1.x, val, acc[ 4]);
        acc[ 5] = __builtin_fmaf(w1.y, val, acc[ 5]);
        acc[ 6] = __builtin_fmaf(w1.z, val, acc[ 6]);
        acc[ 7] = __builtin_fmaf(w1.w, val, acc[ 7]);
        acc[ 8] = __builtin_fmaf(w2.x, val, acc[ 8]);
        acc[ 9] = __builtin_fmaf(w2.y, val, acc[ 9]);
        acc[10] = __builtin_fmaf(w2.z, val, acc[10]);
        acc[11] = __builtin_fmaf(w2.w, val, acc[11]);
        acc[12] = __builtin_fmaf(w3.x, val, acc[12]);
        acc[13] = __builtin_fmaf(w3.y, val, acc[13]);
        acc[14] = __builtin_fmaf(w3.z, val, acc[14]);
        acc[15] = __builtin_fmaf(w3.w, val, acc[15]);
        const float t1 = Cc * s1;
        const float t2 = S  * s1;
        const float ns = __builtin_fmaf(S,  c1,  t1);
        const float nc = __builtin_fmaf(Cc, c1, -t2);
        S = ns; Cc = nc;
    }

    // ---- epilogue: finalize sig in REGISTERS (acc becomes sig) ----
    float amr[NROWS];
    const float i_f = (float)t;
    #pragma unroll
    for (int r = 0; r < NROWS; ++r) {
        float am = 0.0f;
        if (act) {
            const float  nz = noise[(size_t)r*T_LEN + t];
            const float4 eA = envA[r];
            const float4 eB = envB[r];
            const float2 ng = nlg[r];
            float env;
            if      (i_f < eA.x) env = (eA.x > 1.0f) ? i_f * eB.x : 0.0f;
            else if (i_f < eA.y) env = __builtin_fmaf((eB.w-1.0f)*(i_f-eA.x), eB.y, 1.0f);
            else if (i_f < eA.z) env = eB.w;
            else if (i_f < eA.w) env = eB.w * (1.0f - (i_f-eA.z)*eB.z);
            else                 env = 0.0f;
            const float n  = (nz*2.0f - 1.0f) * ng.x;
            acc[r] = ((acc[r] + n) * env) * ng.y;   // final sig, stays in VGPR
            am = fabsf(acc[r]);
        }
        amr[r] = am;
    }

    // ---- per-row wave max-reduce, block reduce, device atomicMax ----
    #pragma unroll
    for (int off = 32; off > 0; off >>= 1) {
        #pragma unroll
        for (int r = 0; r < NROWS; ++r)
            amr[r] = fmaxf(amr[r], __shfl_xor(amr[r], off, 64));
    }
    if ((tid & 63) == 0) {
        const int wid = tid >> 6;
        #pragma unroll
        for (int r = 0; r < NROWS; ++r) redbuf[wid][r] = amr[r];
    }
    __syncthreads();
    if (tid < NROWS) {
        const float m01 = fmaxf(redbuf[0][tid], redbuf[1][tid]);
        const float m23 = fmaxf(redbuf[2][tid], redbuf[3][tid]);
        atomicMax(rowmax + tid, __float_as_uint(fmaxf(m01, m23)));  // device scope
    }
    // __syncthreads drains the atomics (compiler emits s_waitcnt vmcnt(0)
    // before s_barrier) -> this block's RMWs are globally visible after it.
    __syncthreads();

    // ---- hand-rolled grid barrier: arrival counter + s_sleep spin ----
    if (tid == 0) {
        __hip_atomic_fetch_add(counter, 1u, __ATOMIC_ACQ_REL,
                               __HIP_MEMORY_SCOPE_AGENT);
        while (__hip_atomic_load(counter, __ATOMIC_ACQUIRE,
                                 __HIP_MEMORY_SCOPE_AGENT) < (unsigned)NBLK)
            __builtin_amdgcn_s_sleep(8);
    }
    __syncthreads();

    // ---- per-row inverse max (acquire loads past XCD L2s) ----
    if (tid < NROWS) {
        const unsigned mb = __hip_atomic_load(rowmax + tid, __ATOMIC_ACQUIRE,
                                              __HIP_MEMORY_SCOPE_AGENT);
        invsm[tid] = 1.0f / (__uint_as_float(mb) + 1e-5f);  // same as R8/R9
    }
    __syncthreads();

    // ---- single HBM write of the normalized output ----
    if (act) {
        #pragma unroll
        for (int r = 0; r < NROWS; ++r)
            out[(size_t)r*T_LEN + t] = acc[r] * invsm[r];
    }
}

extern "C" void kernel_launch(void* const* d_in, const int* in_sizes, int n_in,
                              void* d_out, int out_size, void* d_ws, size_t ws_size,
                              hipStream_t stream) {
    // inputs: 0=base_audio(unused) 1=harmonic_dist 2=noise_bands 3=adsr 4=gain 5=noise
    const float* harm  = (const float*)d_in[1];
    const float* nbp   = (const float*)d_in[2];
    const float* adsrp = (const float*)d_in[3];
    const float* gainp = (const float*)d_in[4];
    const float* noisp = (const float*)d_in[5];
    float* out = (float*)d_out;
    unsigned int* rowmax  = (unsigned int*)d_ws;        // [16]
    unsigned int* counter = (unsigned int*)d_ws + 16;   // [1]

    hipMemsetAsync(d_ws, 0, 128, stream);   // rowmax + counter
    ddsp_fused<<<dim3(NBLK), dim3(256), 0, stream>>>(
        harm, nbp, adsrp, gainp, noisp, out, rowmax, counter);
}